// Round 14
// baseline (25440.817 us; speedup 1.0000x reference)
//
#include <hip/hip_runtime.h>
#include <hip/hip_bf16.h>
#include <hip/hip_fp16.h>
#include <stdint.h>

typedef _Float16 h2_t  __attribute__((ext_vector_type(2)));
typedef _Float16 f16x8 __attribute__((ext_vector_type(8)));
typedef float    f32x4 __attribute__((ext_vector_type(4)));

#define TSEQ 4096
#define HID  256
#define IN2  512
#define NB   64
#define CH   256
#define NCH  16

__device__ __forceinline__ h2_t bc_h2(uint32_t v){ return __builtin_bit_cast(h2_t, v); }

__device__ __forceinline__ float sigm_(float x){
    return __builtin_amdgcn_rcpf(1.f + __expf(-x));
}
__device__ __forceinline__ float tanh_(float x){
    return 1.f - 2.f*__builtin_amdgcn_rcpf(1.f + __expf(2.f*x));
}
__device__ __forceinline__ void sync_lds(){
    asm volatile("s_waitcnt lgkmcnt(0)\n\ts_barrier" ::: "memory");
}
__device__ __forceinline__ f32x4 mfma16(f16x8 a, f16x8 b, f32x4 c){
    return __builtin_amdgcn_mfma_f32_16x16x32_f16(a, b, c, 0, 0, 0);
}
// extract f16 element i (compile-time const) from a uint4 of 8 packed f16
__device__ __forceinline__ float f16x(uint4 v, int i){
    int wsel = i >> 1;
    uint32_t word = (wsel==0) ? v.x : (wsel==1) ? v.y : (wsel==2) ? v.z : v.w;
    h2_t hh = bc_h2(word);
    return (float)hh[i & 1];
}

// ---------------- prep --------------------------------------------------------------------
// wfrag (r,z B-fragments, resident): idx -> (L, w, t, kt, lane, j), t in [0,12) but rec uses
//   t<8: g=t>>2 (0=r,1=z), sub=t&3; col = w*64 + sub*16 + (lane&15); k = kt*32+(lane>>4)*8+j
// whstream (h~ B-fragments, streamed): idx2 -> (((L*4+w)*32 + kt*4+sub)*64 + lane)*8 + j
__global__ void prep_kernel(const float* __restrict__ Wr, const float* __restrict__ Wz,
                            const float* __restrict__ Wh, const float* __restrict__ emb,
                            const float* __restrict__ br, const float* __restrict__ bz,
                            const float* __restrict__ bh,
                            __half* __restrict__ wfrag, __half* __restrict__ wxt,
                            __half* __restrict__ embf16, float* __restrict__ biasv,
                            __half* __restrict__ whstream)
{
    const long long S0 = 393216LL;           // wfrag f16 count: 2*4*12*8*64*8
    const long long S1 = 2LL*768*256;        // wxt
    const long long S2 = 32000LL*256;        // emb f16
    const long long S3 = 2LL*768;            // biasv
    const long long S4 = 131072LL;           // whstream f16: 2*4*32*64*8
    for (long long idx = (long long)blockIdx.x*256 + threadIdx.x; idx < S0+S1+S2+S3+S4;
         idx += (long long)gridDim.x*256) {
        if (idx < S0) {
            int i    = (int)idx;
            int j    = i & 7;
            int lane = (i >> 3) & 63;
            int kt   = (i >> 9) & 7;
            int rest = i >> 12;              // 0..95
            int t    = rest % 12;
            int w    = (rest / 12) & 3;
            int L    = rest / 48;
            int g = t >> 2, sub = t & 3;
            int col = w*64 + sub*16 + (lane & 15);
            int k   = kt*32 + (lane >> 4)*8 + j;
            const float* Wsrc = (g==0?Wr:(g==1?Wz:Wh)) + (size_t)L*IN2*HID;
            wfrag[idx] = __float2half(Wsrc[(size_t)(256 + k)*HID + col]);
        } else if (idx < S0+S1) {
            int i  = (int)(idx - S0);
            int k  = i & 255;
            int i2 = i >> 8;
            int o  = i2 % 768, L = i2 / 768;
            int g  = o >> 8,   n = o & 255;
            const float* Wsrc = (g==0?Wr:(g==1?Wz:Wh)) + (size_t)L*IN2*HID;
            wxt[i] = __float2half(Wsrc[(size_t)k*HID + n]);
        } else if (idx < S0+S1+S2) {
            int i = (int)(idx - S0 - S1);
            embf16[i] = __float2half(emb[i]);
        } else if (idx < S0+S1+S2+S3) {
            int i = (int)(idx - S0 - S1 - S2);
            int o = i % 768, L = i / 768;
            int g = o >> 8,  n = o & 255;
            const float* bsrc = (g==0?br:(g==1?bz:bh));
            biasv[i] = bsrc[L*HID + n];
        } else {
            int i    = (int)(idx - S0 - S1 - S2 - S3);
            int j    = i & 7;
            int lane = (i >> 3) & 63;
            int fi   = (i >> 9) & 31;        // kt*4+sub
            int w    = (i >> 14) & 3;
            int L    = i >> 16;
            int kt = fi >> 2, sub = fi & 3;
            int col = w*64 + sub*16 + (lane & 15);
            int k   = kt*32 + (lane >> 4)*8 + j;
            whstream[i] = __float2half(Wh[(size_t)L*IN2*HID + (size_t)(256 + k)*HID + col]);
        }
    }
}

// ---------------- x-projection GEMM -------------------------------------------------------
// proj layout: f16 index = (((group*CH+tl)*4 + wave)*64 + lane)*48 + (g*4+sub)*4 + q
__global__ __launch_bounds__(256) void gemm_proj(
    const int* __restrict__ tokens, const __half* __restrict__ embf16,
    const __half* __restrict__ h0chunk, const __half* __restrict__ wxt,
    const float* __restrict__ biasv,
    __half* __restrict__ proj0, __half* __restrict__ proj1, int c0, int c1)
{
    const int Lz = blockIdx.z;
    const int c  = Lz ? c1 : c0;
    if (c < 0 || c >= NCH) return;
    __half* proj = Lz ? proj1 : proj0;

    __shared__ uint4 Ald[128*17];
    __shared__ uint4 Bld[64*17];
    const int tid = threadIdx.x;
    const int mt = blockIdx.x, nt = blockIdx.y;
    const int w = tid >> 6, l = tid & 63, lr = l & 15, lk = l >> 4;
    f32x4 acc[2][4] = {};

#pragma unroll 1
    for (int kh = 0; kh < 2; ++kh) {
        if (kh) __syncthreads();
#pragma unroll
        for (int it = 0; it < 8; ++it) {
            int idx = it*256 + tid;
            int row = idx >> 4, u4 = idx & 15;
            int grow = mt*128 + row;
            const __half* src;
            if (Lz == 0) {
                int b = grow >> 8, tl = grow & (CH-1);
                int tok = tokens[(size_t)b*TSEQ + c*CH + tl];
                src = embf16 + (size_t)tok*HID;
            } else {
                src = h0chunk + (size_t)grow*HID;
            }
            Ald[row*17 + u4] = ((const uint4*)(src + kh*128))[u4];
        }
#pragma unroll
        for (int it = 0; it < 4; ++it) {
            int idx = it*256 + tid;
            int col = idx >> 4, u4 = idx & 15;
            const __half* src = wxt + ((size_t)(Lz*768 + nt*64 + col))*HID + kh*128;
            Bld[col*17 + u4] = ((const uint4*)src)[u4];
        }
        __syncthreads();
        const _Float16* A = (const _Float16*)Ald;
        const _Float16* B = (const _Float16*)Bld;
#pragma unroll
        for (int kb = 0; kb < 4; ++kb) {
            int k0 = kb*32;
            f16x8 af[2], bf[4];
#pragma unroll
            for (int fm = 0; fm < 2; ++fm) {
                int row = w*32 + fm*16 + lr;
                af[fm] = *(const f16x8*)(A + row*136 + k0 + lk*8);
            }
#pragma unroll
            for (int fn = 0; fn < 4; ++fn) {
                int col = fn*16 + lr;
                bf[fn] = *(const f16x8*)(B + col*136 + k0 + lk*8);
            }
#pragma unroll
            for (int fm = 0; fm < 2; ++fm)
#pragma unroll
                for (int fn = 0; fn < 4; ++fn)
                    acc[fm][fn] = mfma16(af[fm], bf[fn], acc[fm][fn]);
        }
    }
#pragma unroll
    for (int fm = 0; fm < 2; ++fm)
#pragma unroll
        for (int fn = 0; fn < 4; ++fn)
#pragma unroll
            for (int q = 0; q < 4; ++q) {
                int row = mt*128 + w*32 + fm*16 + lk*4 + q;
                int col = nt*64 + fn*16 + lr;
                float v = acc[fm][fn][q] + biasv[Lz*768 + col];
                int b = row >> 8, tl = row & 255;
                int group = b >> 4, s = b & 15;
                int wv  = (col & 255) >> 6;
                int sub = (col >> 4) & 3;
                int g   = col >> 8;
                int lane2 = ((s >> 2) << 4) | (col & 15);
                int qq  = s & 3;
                size_t off = (((size_t)(group*CH + tl)*4 + wv)*64 + lane2)*48
                           + (size_t)(g*4 + sub)*4 + qq;
                proj[off] = __float2half(v);
            }
}

// ---------------- MFMA recurrence ---------------------------------------------------------
// 8 blocks = 2 layers x 4 groups of 16 samples. 256 thr (4 waves), 1 wave/SIMD (512 unified
// regs/wave). Resident: r,z B-fragments = 64 frags = 256 regs. h~ fragments STREAMED from
// L2 each step (3-deep ring, 48 regs in flight). Peak demand ~410 < 450 (m08 no-spill line).
__global__ __launch_bounds__(256)
__attribute__((amdgpu_waves_per_eu(1, 1)))
void rec_mfma(const __half* __restrict__ wfrag, const __half* __restrict__ whstream,
              const __half* __restrict__ proj0, const __half* __restrict__ proj1,
              __half* __restrict__ h0chunk, float* __restrict__ hstate,
              const float* __restrict__ Wfc, const float* __restrict__ bfc,
              float* __restrict__ out, int c0, int c1)
{
    __shared__ __align__(16) _Float16 s_h[4096];   // [16 samples][256] swizzled
    __shared__ __align__(16) _Float16 s_rh[4096];
    __shared__ float s_head[4096];                 // [16][256] f32 final h

    const int L   = blockIdx.x >> 2;
    const int grp = blockIdx.x & 3;
    const int c   = L ? c1 : c0;
    if (c < 0 || c >= NCH) return;

    const int tid = threadIdx.x;
    const int w   = tid >> 6;
    const int l   = tid & 63;
    const int lr  = l & 15;
    const int lk  = l >> 4;

    // resident r,z B-fragments: wf[t][kt], t = g*4+sub (g=0 r, g=1 z)
    f16x8 wf[8][8];
    {
        const __half* wb = wfrag + ((size_t)(L*4 + w)*96)*512 + (size_t)l*8;
#pragma unroll
        for (int t = 0; t < 8; ++t)
#pragma unroll
            for (int kt = 0; kt < 8; ++kt)
                wf[t][kt] = *(const f16x8*)(wb + (size_t)(t*8 + kt)*512);
    }

    // persistent h (D-layout): hreg[sub][q] holds (s = lk*4+q, col = 64w + sub*16 + lr)
    float hreg[4][4];
#pragma unroll
    for (int sub = 0; sub < 4; ++sub)
#pragma unroll
        for (int q = 0; q < 4; ++q) {
            int s = lk*4 + q, col = w*64 + sub*16 + lr;
            hreg[sub][q] = (c == 0) ? 0.f
                : hstate[((size_t)(L*NB + grp*16 + s))*HID + col];
            int addr = s*512 + ((col*2) ^ ((s & 7) << 4));
            *(_Float16*)((char*)s_h + addr) = (_Float16)hreg[sub][q];
        }
    __syncthreads();

    const __half* prow = (L ? proj1 : proj0)
        + ((size_t)grp*CH*4 + w)*3072 + (size_t)l*48;
    const __half* whp_base = whstream + (size_t)(L*4 + w)*32*512 + (size_t)l*8;

#pragma unroll 1
    for (int tl = 0; tl < CH; ++tl) {
        // launder the stream pointer so loop-invariant loads are NOT hoisted (reg budget!)
        const __half* whp = whp_base;
        asm("" : "+v"(whp));
#define WHLD(KT, SUB) (*(const f16x8*)(whp + (size_t)((KT)*4 + (SUB))*512))
        // issue first 3 kt-batches of the h~ stream; phase A covers their latency
        f16x8 wb0[4], wb1[4], wb2[4];
#pragma unroll
        for (int s4 = 0; s4 < 4; ++s4) { wb0[s4] = WHLD(0, s4); }
#pragma unroll
        for (int s4 = 0; s4 < 4; ++s4) { wb1[s4] = WHLD(1, s4); }
#pragma unroll
        for (int s4 = 0; s4 < 4; ++s4) { wb2[s4] = WHLD(2, s4); }

        const __half* pp = prow + (size_t)tl*12288;
        uint4 pjr0 = *(const uint4*)(pp);        // r: sub 0-1
        uint4 pjr1 = *(const uint4*)(pp + 8);    // r: sub 2-3
        uint4 pjz0 = *(const uint4*)(pp + 16);   // z: sub 0-1
        uint4 pjz1 = *(const uint4*)(pp + 24);   // z: sub 2-3

        // A-fragments of h (s = lr)
        f16x8 ha[8];
#pragma unroll
        for (int kt = 0; kt < 8; ++kt) {
            int addr = lr*512 + ((kt*64 + lk*16) ^ ((lr & 7) << 4));
            ha[kt] = *(const f16x8*)((const char*)s_h + addr);
        }

        uint32_t zpk[4][2];
        // phase A: r,z — two groups of 4 interleaved MFMA chains
#pragma unroll
        for (int g2 = 0; g2 < 2; ++g2) {
            const int s0 = g2*2, s1 = g2*2 + 1;
            f32x4 ar0 = {}, az0 = {}, ar1 = {}, az1 = {};
#pragma unroll
            for (int kt = 0; kt < 8; ++kt) {
                ar0 = mfma16(ha[kt], wf[s0][kt],     ar0);
                az0 = mfma16(ha[kt], wf[4 + s0][kt], az0);
                ar1 = mfma16(ha[kt], wf[s1][kt],     ar1);
                az1 = mfma16(ha[kt], wf[4 + s1][kt], az1);
            }
#pragma unroll
            for (int h2i = 0; h2i < 2; ++h2i) {
                const int sub = g2*2 + h2i;
                f32x4 ar = h2i ? ar1 : ar0;
                f32x4 az = h2i ? az1 : az0;
                uint4 vr = (sub < 2) ? pjr0 : pjr1;
                uint4 vz = (sub < 2) ? pjz0 : pjz1;
                float zq[4];
#pragma unroll
                for (int q = 0; q < 4; ++q) {
                    int s = lk*4 + q, col = w*64 + sub*16 + lr;
                    float r = sigm_(ar[q] + f16x(vr, (sub & 1)*4 + q));
                    zq[q]   = sigm_(az[q] + f16x(vz, (sub & 1)*4 + q));
                    float rh = r * hreg[sub][q];
                    int addr = s*512 + ((col*2) ^ ((s & 7) << 4));
                    *(_Float16*)((char*)s_rh + addr) = (_Float16)rh;
                }
                h2_t z01; z01[0] = (_Float16)zq[0]; z01[1] = (_Float16)zq[1];
                h2_t z23; z23[0] = (_Float16)zq[2]; z23[1] = (_Float16)zq[3];
                zpk[sub][0] = __builtin_bit_cast(uint32_t, z01);
                zpk[sub][1] = __builtin_bit_cast(uint32_t, z23);
            }
        }

        uint4 pjh0 = *(const uint4*)(pp + 32);   // h~: sub 0-1
        uint4 pjh1 = *(const uint4*)(pp + 40);   // h~: sub 2-3
        sync_lds();

        // phase B: candidate over r*h; wh streamed (ring: 0,1,2 loaded; refill 3..7)
        f16x8 ra[8];
#pragma unroll
        for (int kt = 0; kt < 8; ++kt) {
            int addr = lr*512 + ((kt*64 + lk*16) ^ ((lr & 7) << 4));
            ra[kt] = *(const f16x8*)((const char*)s_rh + addr);
        }
        f32x4 ah[4] = {};
#define MFMA4(KT, BUF) \
        ah[0] = mfma16(ra[KT], BUF[0], ah[0]); \
        ah[1] = mfma16(ra[KT], BUF[1], ah[1]); \
        ah[2] = mfma16(ra[KT], BUF[2], ah[2]); \
        ah[3] = mfma16(ra[KT], BUF[3], ah[3]);
#define REFILL(BUF, KT) \
        BUF[0] = WHLD(KT,0); BUF[1] = WHLD(KT,1); BUF[2] = WHLD(KT,2); BUF[3] = WHLD(KT,3);
        MFMA4(0, wb0) REFILL(wb0, 3)
        MFMA4(1, wb1) REFILL(wb1, 4)
        MFMA4(2, wb2) REFILL(wb2, 5)
        MFMA4(3, wb0) REFILL(wb0, 6)
        MFMA4(4, wb1) REFILL(wb1, 7)
        MFMA4(5, wb2)
        MFMA4(6, wb0)
        MFMA4(7, wb1)
#undef MFMA4
#undef REFILL
#undef WHLD

#pragma unroll
        for (int sub = 0; sub < 4; ++sub) {
            uint4 vh = (sub < 2) ? pjh0 : pjh1;
#pragma unroll
            for (int q = 0; q < 4; ++q) {
                int s = lk*4 + q, col = w*64 + sub*16 + lr;
                float th = tanh_(ah[sub][q] + f16x(vh, (sub & 1)*4 + q));
                h2_t zz = bc_h2(zpk[sub][q >> 1]);
                float z = (float)zz[q & 1];
                float h = hreg[sub][q];
                h += z*(th - h);
                hreg[sub][q] = h;
                int addr = s*512 + ((col*2) ^ ((s & 7) << 4));
                *(_Float16*)((char*)s_h + addr) = (_Float16)h;
                if (tl == CH-1) {
                    s_head[s*256 + col] = h;
                    hstate[((size_t)(L*NB + grp*16 + s))*HID + col] = h;
                }
            }
        }
        sync_lds();

        // h0chunk: coalesced staging copy of this step's s_h (L0 only)
        if (L == 0) {
            int idx2 = tid << 1;
            int s2 = idx2 >> 5;          // [0,16)
            int m  = idx2 & 31;          // even
            const char* srcb = (const char*)s_h + s2*512;
            uint4 v0 = *(const uint4*)(srcb + ((m*16)       ^ ((s2 & 7) << 4)));
            uint4 v1 = *(const uint4*)(srcb + (((m + 1)*16) ^ ((s2 & 7) << 4)));
            uint4* dst = (uint4*)(h0chunk + ((size_t)(grp*16 + s2)*CH + tl)*HID) + m;
            dst[0] = v0;
            dst[1] = v1;
        }
    }

    // classification head (L1, last chunk) — from block-local s_head
    if (L == 1 && c == NCH-1) {
        __syncthreads();
        if (tid < 64) {
            int s = tid >> 2, part = tid & 3;
            const float* hrow = s_head + s*256 + part*64;
            float p0 = 0.f, p1 = 0.f;
#pragma unroll 4
            for (int i = 0; i < 64; ++i) {
                float hv = hrow[i];
                p0 += hv * Wfc[(part*64 + i)*2 + 0];
                p1 += hv * Wfc[(part*64 + i)*2 + 1];
            }
            p0 += __shfl_xor(p0, 1); p0 += __shfl_xor(p0, 2);
            p1 += __shfl_xor(p1, 1); p1 += __shfl_xor(p1, 2);
            if (part == 0) {
                out[(grp*16 + s)*2 + 0] = p0 + bfc[0];
                out[(grp*16 + s)*2 + 1] = p1 + bfc[1];
            }
        }
    }
}

// ---------------- host ----------------
extern "C" void kernel_launch(void* const* d_in, const int* in_sizes, int n_in,
                              void* d_out, int out_size, void* d_ws, size_t ws_size,
                              hipStream_t stream) {
    const int*   tokens = (const int*)  d_in[0];
    const float* emb    = (const float*)d_in[1];
    const float* Wr     = (const float*)d_in[2];
    const float* br     = (const float*)d_in[3];
    const float* Wz     = (const float*)d_in[4];
    const float* bz     = (const float*)d_in[5];
    const float* Wh     = (const float*)d_in[6];
    const float* bh     = (const float*)d_in[7];
    const float* Wfc    = (const float*)d_in[8];
    const float* bfc    = (const float*)d_in[9];
    float* out = (float*)d_out;

    char* ws = (char*)d_ws;
    __half*   wfrag   = (__half*)(ws + 0);                //    786,432 B
    __half*   wxt     = (__half*)(ws + (1u<<20));         //    786,432 B
    __half*   embf16  = (__half*)(ws + (2u<<20));         // 16,384,000 B
    __half*   proj0   = (__half*)(ws + 18874368u);        // 25,165,824 B
    __half*   proj1   = (__half*)(ws + 44040192u);        // 25,165,824 B
    __half*   h0chunk = (__half*)(ws + 69206016u);        //  8,388,608 B
    float*    hstate  = (float*)(ws + 77594624u);         //    131,072 B
    float*    biasv   = (float*)(ws + 77725696u);         //      6,144 B
    __half*   whstream= (__half*)(ws + 77731840u);        //    262,144 B (~78 MB total)

    prep_kernel<<<2048, 256, 0, stream>>>(Wr, Wz, Wh, emb, br, bz, bh,
                                          wfrag, wxt, embf16, biasv, whstream);

    dim3 ggrid(128, 12, 2);
    for (int c = 0; c <= NCH; ++c) {
        int cc0 = (c < NCH) ? c : -1;
        int cc1 = c - 1;
        gemm_proj<<<ggrid, 256, 0, stream>>>(tokens, embf16, h0chunk, wxt, biasv,
                                             proj0, proj1, cc0, cc1);
        rec_mfma<<<8, 256, 0, stream>>>(wfrag, whstream, proj0, proj1, h0chunk, hstate,
                                        Wfc, bfc, out, cc0, cc1);
    }
}

// Round 15
// 5919.427 us; speedup vs baseline: 4.2979x; 4.2979x over previous
//
#include <hip/hip_runtime.h>
#include <hip/hip_bf16.h>
#include <hip/hip_fp16.h>
#include <stdint.h>

typedef _Float16 h2_t  __attribute__((ext_vector_type(2)));
typedef _Float16 f16x8 __attribute__((ext_vector_type(8)));
typedef float    f32x4 __attribute__((ext_vector_type(4)));

#define TSEQ 4096
#define HID  256
#define IN2  512
#define NB   64
#define CH   256
#define NCH  16

__device__ __forceinline__ h2_t bc_h2(uint32_t v){ return __builtin_bit_cast(h2_t, v); }
__device__ __forceinline__ uint32_t pk2(float a, float b){
    h2_t p; p[0] = (_Float16)a; p[1] = (_Float16)b;
    return __builtin_bit_cast(uint32_t, p);
}
__device__ __forceinline__ float quad_reduce(float x){
    float t;
    t = __builtin_bit_cast(float, __builtin_amdgcn_mov_dpp(__builtin_bit_cast(int, x), 0xB1, 0xF, 0xF, true));
    x += t;
    t = __builtin_bit_cast(float, __builtin_amdgcn_mov_dpp(__builtin_bit_cast(int, x), 0x4E, 0xF, 0xF, true));
    x += t;
    return x;
}
__device__ __forceinline__ float sigm_(float x){
    return __builtin_amdgcn_rcpf(1.f + __expf(-x));
}
__device__ __forceinline__ float tanh_(float x){
    return 1.f - 2.f*__builtin_amdgcn_rcpf(1.f + __expf(2.f*x));
}
__device__ __forceinline__ void sync_lds(){
    asm volatile("s_waitcnt lgkmcnt(0)\n\ts_barrier" ::: "memory");
}
__device__ __forceinline__ f32x4 mfma16(f16x8 a, f16x8 b, f32x4 c){
    return __builtin_amdgcn_mfma_f32_16x16x32_f16(a, b, c, 0, 0, 0);
}

// ---------------- prep: pack recurrent weights (pair layout), wxt, biases -------------------
// wpack word (g, kk, n), kk in [0,128): ( W[256+kk][n], W[256+128+kk][n] ) f16 pair
//   -> matches pair-packed s_h: word j = (h[j], h[j+128]).
// wxt[L][o][k]: L0 identity k; L1 k-permuted pi(k)=(k&1)?128+(k>>1):(k>>1) to match the
//   pair-interleaved h0chunk rows.
__global__ void prep_kernel(const float* __restrict__ Wr, const float* __restrict__ Wz,
                            const float* __restrict__ Wh,
                            const float* __restrict__ br, const float* __restrict__ bz,
                            const float* __restrict__ bh,
                            uint32_t* __restrict__ wpack, __half* __restrict__ wxt,
                            float* __restrict__ biasv)
{
    const int S0 = 196608;    // wpack u32: 2*3*128*256
    const int S1 = 393216;    // wxt f16:  2*768*256
    const int S3 = 1536;      // biasv
    for (int idx = blockIdx.x*256 + threadIdx.x; idx < S0+S1+S3; idx += gridDim.x*256) {
        if (idx < S0) {
            int n  = idx & 255;
            int kk = (idx >> 8) & 127;
            int t  = idx >> 15;            // 0..5 = L*3+g
            int g = t % 3, L = t / 3;
            const float* Wsrc = (g==0?Wr:(g==1?Wz:Wh)) + (size_t)L*IN2*HID;
            h2_t p;
            p[0] = (_Float16)Wsrc[(256 + kk)*HID + n];
            p[1] = (_Float16)Wsrc[(256 + 128 + kk)*HID + n];
            wpack[idx] = __builtin_bit_cast(uint32_t, p);
        } else if (idx < S0+S1) {
            int i  = idx - S0;
            int k  = i & 255;
            int i2 = i >> 8;               // 0..1535
            int o  = i2 % 768, L = i2 / 768;
            int g  = o >> 8,   n = o & 255;
            const float* Wsrc = (g==0?Wr:(g==1?Wz:Wh)) + (size_t)L*IN2*HID;
            int ksrc = (L==1) ? ((k & 1) ? 128 + (k >> 1) : (k >> 1)) : k;
            wxt[i] = __float2half(Wsrc[(size_t)ksrc*HID + n]);
        } else {
            int i = idx - S0 - S1;         // [0,1536)
            int o = i % 768, L = i / 768;
            int g = o >> 8,  n = o & 255;
            const float* bsrc = (g==0?br:(g==1?bz:bh));
            biasv[i] = bsrc[L*HID + n];
        }
    }
}

// ---------------- fused step: blocks 0-127 = recurrence, 128-1663 = x-proj GEMM -------------
// Launch i: rec-L0 chunk i (proj0[i&1] -> h0[i&1]); rec-L1 chunk i-2 (proj1[i&1]);
//           gemm-L0 chunk i+1 -> proj0[(i+1)&1]; gemm-L1 chunk i-1 (h0[(i-1)&1]) -> proj1[(i+1)&1].
// proj row = 1536 B: uint2 at u32 idx nb*2 = (r pair, z pair); u32 at 256+nb = h~ pair.
__global__ __launch_bounds__(512)
__attribute__((amdgpu_waves_per_eu(2, 2)))
void fused_step(const int* __restrict__ tokens, const float* __restrict__ emb,
                const uint32_t* __restrict__ wpack, const __half* __restrict__ wxt,
                const float* __restrict__ biasv,
                __half* __restrict__ proj0a, __half* __restrict__ proj0b,
                __half* __restrict__ proj1a, __half* __restrict__ proj1b,
                __half* __restrict__ h0a, __half* __restrict__ h0b,
                float* __restrict__ hstate,
                const float* __restrict__ Wfc, const float* __restrict__ bfc,
                float* __restrict__ out, int step)
{
    __shared__ __align__(16) uint32_t s_h[128];    // word j = (h[j], h[j+128]) f16
    __shared__ __align__(16) uint32_t s_rh[128];
    __shared__ float s_head[256];
    __shared__ uint4 Ald[128*17];
    __shared__ uint4 Bld[128*17];

    const int tid = threadIdx.x;

    if (blockIdx.x < 128) {
        // ======================= recurrence role (r10 structure) =======================
        const int L = blockIdx.x >> 6;
        const int b = blockIdx.x & 63;
        const int c = L ? (step - 2) : step;
        if (c < 0 || c >= NCH) return;
        const uint32_t* projr = (const uint32_t*)(L ? ((step & 1) ? proj1b : proj1a)
                                                    : ((step & 1) ? proj0b : proj0a));
        uint32_t* h0w = (uint32_t*)((step & 1) ? h0b : h0a);

        const int k4  = tid & 3;
        const int nb  = tid >> 2;            // [0,128)
        const bool wlead = (k4 == 0);

        // weights, rotation-permuted: reg i = u*4+j <-> pair-word kk = k4*32 + ((u+k4)&7)*4 + j
        uint32_t wr_[2][32], wz_[2][32], wh_[2][32];
        {
            const uint32_t* wb = wpack + (size_t)(L*3*128)*256;
#pragma unroll
            for (int u = 0; u < 8; ++u)
#pragma unroll
                for (int j = 0; j < 4; ++j) {
                    int i  = u*4 + j;
                    int kk = k4*32 + (((u + k4) & 7)*4 + j);
                    wr_[0][i] = wb[(      kk)*256 + nb      ];
                    wr_[1][i] = wb[(      kk)*256 + nb + 128];
                    wz_[0][i] = wb[(128 + kk)*256 + nb      ];
                    wz_[1][i] = wb[(128 + kk)*256 + nb + 128];
                    wh_[0][i] = wb[(256 + kk)*256 + nb      ];
                    wh_[1][i] = wb[(256 + kk)*256 + nb + 128];
                }
        }
#pragma unroll
        for (int i = 0; i < 32; ++i) {
            asm volatile("" : "+v"(wr_[0][i]), "+v"(wr_[1][i]), "+v"(wz_[0][i]),
                              "+v"(wz_[1][i]), "+v"(wh_[0][i]), "+v"(wh_[1][i]));
        }

        float h0f, h1f;
        if (c == 0) { h0f = 0.f; h1f = 0.f; }
        else {
            h0f = hstate[(size_t)(L*NB + b)*HID + nb];
            h1f = hstate[(size_t)(L*NB + b)*HID + nb + 128];
        }
        if (wlead) s_h[nb] = pk2(h0f, h1f);
        __syncthreads();

        const uint32_t* prow = projr + (size_t)b*CH*384;
        const uint4* hq4  = ((const uint4*)s_h)  + k4*8;   // quarter = 8 uint4 (128B)
        const uint4* rq4  = ((const uint4*)s_rh) + k4*8;

        uint2    pjrz = *(const uint2*)(prow + nb*2);
        uint32_t pjh  = prow[256 + nb];

#pragma unroll 1
        for (int tl = 0; tl < CH; ++tl) {
            // prefetch next step's proj (raw barriers keep loads in flight)
            int tn = (tl + 1 < CH) ? tl + 1 : tl;
            const uint32_t* pn = prow + (size_t)tn*384;
            uint2    pjrzN = *(const uint2*)(pn + nb*2);
            uint32_t pjhN  = pn[256 + nb];

            // phase A: r,z over h; rotated b128 reads (conflict-free across k4)
            float ar0=0.f, ar1=0.f, az0=0.f, az1=0.f;
#pragma unroll
            for (int u = 0; u < 8; ++u) {
                uint4 hv = hq4[(u + k4) & 7];
                int i = u*4;
                ar0 = __builtin_amdgcn_fdot2(bc_h2(wr_[0][i  ]), bc_h2(hv.x), ar0, false);
                ar1 = __builtin_amdgcn_fdot2(bc_h2(wr_[1][i  ]), bc_h2(hv.x), ar1, false);
                az0 = __builtin_amdgcn_fdot2(bc_h2(wz_[0][i  ]), bc_h2(hv.x), az0, false);
                az1 = __builtin_amdgcn_fdot2(bc_h2(wz_[1][i  ]), bc_h2(hv.x), az1, false);
                ar0 = __builtin_amdgcn_fdot2(bc_h2(wr_[0][i+1]), bc_h2(hv.y), ar0, false);
                ar1 = __builtin_amdgcn_fdot2(bc_h2(wr_[1][i+1]), bc_h2(hv.y), ar1, false);
                az0 = __builtin_amdgcn_fdot2(bc_h2(wz_[0][i+1]), bc_h2(hv.y), az0, false);
                az1 = __builtin_amdgcn_fdot2(bc_h2(wz_[1][i+1]), bc_h2(hv.y), az1, false);
                ar0 = __builtin_amdgcn_fdot2(bc_h2(wr_[0][i+2]), bc_h2(hv.z), ar0, false);
                ar1 = __builtin_amdgcn_fdot2(bc_h2(wr_[1][i+2]), bc_h2(hv.z), ar1, false);
                az0 = __builtin_amdgcn_fdot2(bc_h2(wz_[0][i+2]), bc_h2(hv.z), az0, false);
                az1 = __builtin_amdgcn_fdot2(bc_h2(wz_[1][i+2]), bc_h2(hv.z), az1, false);
                ar0 = __builtin_amdgcn_fdot2(bc_h2(wr_[0][i+3]), bc_h2(hv.w), ar0, false);
                ar1 = __builtin_amdgcn_fdot2(bc_h2(wr_[1][i+3]), bc_h2(hv.w), ar1, false);
                az0 = __builtin_amdgcn_fdot2(bc_h2(wz_[0][i+3]), bc_h2(hv.w), az0, false);
                az1 = __builtin_amdgcn_fdot2(bc_h2(wz_[1][i+3]), bc_h2(hv.w), az1, false);
            }
            ar0 = quad_reduce(ar0); ar1 = quad_reduce(ar1);
            az0 = quad_reduce(az0); az1 = quad_reduce(az1);

            h2_t pjr = bc_h2(pjrz.x), pjz = bc_h2(pjrz.y);
            float r0 = sigm_(ar0 + (float)pjr[0]);
            float r1 = sigm_(ar1 + (float)pjr[1]);
            float z0 = sigm_(az0 + (float)pjz[0]);
            float z1 = sigm_(az1 + (float)pjz[1]);
            if (wlead) s_rh[nb] = pk2(r0*h0f, r1*h1f);
            sync_lds();

            // phase B: candidate over r*h; same rotation
            float ah0a=0.f, ah0b=0.f, ah1a=0.f, ah1b=0.f;
#pragma unroll
            for (int u = 0; u < 8; ++u) {
                uint4 rv = rq4[(u + k4) & 7];
                int i = u*4;
                ah0a = __builtin_amdgcn_fdot2(bc_h2(wh_[0][i  ]), bc_h2(rv.x), ah0a, false);
                ah1a = __builtin_amdgcn_fdot2(bc_h2(wh_[1][i  ]), bc_h2(rv.x), ah1a, false);
                ah0b = __builtin_amdgcn_fdot2(bc_h2(wh_[0][i+1]), bc_h2(rv.y), ah0b, false);
                ah1b = __builtin_amdgcn_fdot2(bc_h2(wh_[1][i+1]), bc_h2(rv.y), ah1b, false);
                ah0a = __builtin_amdgcn_fdot2(bc_h2(wh_[0][i+2]), bc_h2(rv.z), ah0a, false);
                ah1a = __builtin_amdgcn_fdot2(bc_h2(wh_[1][i+2]), bc_h2(rv.z), ah1a, false);
                ah0b = __builtin_amdgcn_fdot2(bc_h2(wh_[0][i+3]), bc_h2(rv.w), ah0b, false);
                ah1b = __builtin_amdgcn_fdot2(bc_h2(wh_[1][i+3]), bc_h2(rv.w), ah1b, false);
            }
            float ah0 = quad_reduce(ah0a + ah0b);
            float ah1 = quad_reduce(ah1a + ah1b);

            h2_t pjh2 = bc_h2(pjh);
            float t0 = tanh_(ah0 + (float)pjh2[0]);
            float t1 = tanh_(ah1 + (float)pjh2[1]);
            h0f += z0*(t0 - h0f);
            h1f += z1*(t1 - h1f);
            if (wlead) {
                uint32_t w2 = pk2(h0f, h1f);
                s_h[nb] = w2;
                if (L == 0)
                    h0w[((size_t)b*CH + tl)*128 + nb] = w2;
            }
            pjrz = pjrzN; pjh = pjhN;
            sync_lds();
        }

        if (wlead) {
            hstate[(size_t)(L*NB + b)*HID + nb]       = h0f;
            hstate[(size_t)(L*NB + b)*HID + nb + 128] = h1f;
        }

        if (L == 1 && c == NCH-1) {
            if (wlead) { s_head[nb] = h0f; s_head[nb+128] = h1f; }
            __syncthreads();
            if (tid < 64) {
                float p0 = 0.f, p1 = 0.f;
#pragma unroll
                for (int m = 0; m < 4; ++m) {
                    float hv2 = s_head[tid + 64*m];
                    p0 += hv2 * Wfc[(tid+64*m)*2+0];
                    p1 += hv2 * Wfc[(tid+64*m)*2+1];
                }
#pragma unroll
                for (int d = 1; d < 64; d <<= 1) { p0 += __shfl_xor(p0, d); p1 += __shfl_xor(p1, d); }
                if (tid == 0) { out[b*2+0] = p0 + bfc[0]; out[b*2+1] = p1 + bfc[1]; }
            }
        }
    } else {
        // ======================= GEMM role (x-projections) =======================
        int gb = blockIdx.x - 128;
        const int Lz = (gb >= 768) ? 1 : 0;
        gb -= Lz * 768;
        const int mt = gb / 6, nt = gb % 6;          // 128 row-tiles x 6 col-tiles
        const int c = Lz ? (step - 1) : (step + 1);
        if (c < 0 || c >= NCH) return;
        __half* projw = Lz ? (((step + 1) & 1) ? proj1b : proj1a)
                           : (((step + 1) & 1) ? proj0b : proj0a);
        const __half* h0r = ((step - 1) & 1) ? h0b : h0a;   // Lz==1 implies step>=1

        const int w  = tid >> 6;
        const int wm = w >> 2, wn = w & 3;
        const int l  = tid & 63, lr = l & 15, lk = l >> 4;
        f32x4 acc[4][2] = {};

#pragma unroll 1
        for (int kh = 0; kh < 2; ++kh) {
            if (kh) __syncthreads();
            if (Lz == 0) {
                // A from f32 emb (convert inline, RTZ)
#pragma unroll
                for (int it = 0; it < 4; ++it) {
                    int idx = it*512 + tid;
                    int row = idx >> 4, seg = idx & 15;
                    int grow = mt*128 + row;
                    int bb = grow >> 8, tl = grow & 255;
                    int tok = tokens[(size_t)bb*TSEQ + c*CH + tl];
                    const float* s = emb + (size_t)tok*HID + kh*128 + seg*8;
                    float4 f0 = *(const float4*)s;
                    float4 f1 = *(const float4*)(s + 4);
                    uint4 v;
                    v.x = __builtin_bit_cast(uint32_t, __builtin_amdgcn_cvt_pkrtz(f0.x, f0.y));
                    v.y = __builtin_bit_cast(uint32_t, __builtin_amdgcn_cvt_pkrtz(f0.z, f0.w));
                    v.z = __builtin_bit_cast(uint32_t, __builtin_amdgcn_cvt_pkrtz(f1.x, f1.y));
                    v.w = __builtin_bit_cast(uint32_t, __builtin_amdgcn_cvt_pkrtz(f1.z, f1.w));
                    Ald[row*17 + seg] = v;
                }
            } else {
                // A from h0chunk (f16, pair-interleaved rows; wxt is k-permuted to match)
#pragma unroll
                for (int it = 0; it < 4; ++it) {
                    int idx = it*512 + tid;
                    int row = idx >> 4, u4 = idx & 15;
                    int grow = mt*128 + row;
                    const __half* src = h0r + (size_t)grow*HID + kh*128;
                    Ald[row*17 + u4] = ((const uint4*)src)[u4];
                }
            }
#pragma unroll
            for (int it = 0; it < 4; ++it) {
                int idx = it*512 + tid;
                int col = idx >> 4, u4 = idx & 15;
                const __half* src = wxt + ((size_t)(Lz*768 + nt*128 + col))*HID + kh*128;
                Bld[col*17 + u4] = ((const uint4*)src)[u4];
            }
            __syncthreads();
            const _Float16* A = (const _Float16*)Ald;
            const _Float16* B = (const _Float16*)Bld;
#pragma unroll
            for (int kb = 0; kb < 4; ++kb) {
                int k0 = kb*32;
                f16x8 af[4], bf[2];
#pragma unroll
                for (int fm = 0; fm < 4; ++fm)
                    af[fm] = *(const f16x8*)(A + (wm*64 + fm*16 + lr)*136 + k0 + lk*8);
#pragma unroll
                for (int fn = 0; fn < 2; ++fn)
                    bf[fn] = *(const f16x8*)(B + (wn*32 + fn*16 + lr)*136 + k0 + lk*8);
#pragma unroll
                for (int fm = 0; fm < 4; ++fm)
#pragma unroll
                    for (int fn = 0; fn < 2; ++fn)
                        acc[fm][fn] = mfma16(af[fm], bf[fn], acc[fm][fn]);
            }
        }
        // epilogue: C/D layout col=lane&15, row=(lane>>4)*4+q; fold bias; packed row write
#pragma unroll
        for (int fm = 0; fm < 4; ++fm)
#pragma unroll
            for (int fn = 0; fn < 2; ++fn)
#pragma unroll
                for (int q = 0; q < 4; ++q) {
                    int row = mt*128 + wm*64 + fm*16 + lk*4 + q;
                    int col = nt*128 + wn*32 + fn*16 + lr;
                    float v = acc[fm][fn][q] + biasv[Lz*768 + col];
                    int nb2 = col & 127, g = col >> 8, hf = (col >> 7) & 1;
                    int fidx = (g == 2) ? (512 + nb2*2 + hf) : (nb2*4 + g*2 + hf);
                    projw[(size_t)row*768 + fidx] = __float2half(v);
                }
    }
}

// ---------------- host ----------------
extern "C" void kernel_launch(void* const* d_in, const int* in_sizes, int n_in,
                              void* d_out, int out_size, void* d_ws, size_t ws_size,
                              hipStream_t stream) {
    const int*   tokens = (const int*)  d_in[0];
    const float* emb    = (const float*)d_in[1];
    const float* Wr     = (const float*)d_in[2];
    const float* br     = (const float*)d_in[3];
    const float* Wz     = (const float*)d_in[4];
    const float* bz     = (const float*)d_in[5];
    const float* Wh     = (const float*)d_in[6];
    const float* bh     = (const float*)d_in[7];
    const float* Wfc    = (const float*)d_in[8];
    const float* bfc    = (const float*)d_in[9];
    float* out = (float*)d_out;

    char* ws = (char*)d_ws;
    uint32_t* wpack  = (uint32_t*)(ws + 0);               //     786,432 B
    __half*   wxt    = (__half*)(ws +    786432u);        //     786,432 B
    __half*   proj0a = (__half*)(ws +   1572864u);        //  25,165,824 B
    __half*   proj0b = (__half*)(ws +  26738688u);        //  25,165,824 B
    __half*   proj1a = (__half*)(ws +  51904512u);        //  25,165,824 B
    __half*   proj1b = (__half*)(ws +  77070336u);        //  25,165,824 B
    __half*   h0a    = (__half*)(ws + 102236160u);        //   8,388,608 B
    __half*   h0b    = (__half*)(ws + 110624768u);        //   8,388,608 B
    float*    hstate = (float*)(ws + 119013376u);         //     131,072 B
    float*    biasv  = (float*)(ws + 119144448u);         //       6,144 B (~113.6 MiB total)

    prep_kernel<<<1024, 256, 0, stream>>>(Wr, Wz, Wh, br, bz, bh, wpack, wxt, biasv);

    for (int i = -1; i <= 17; ++i) {
        fused_step<<<1664, 512, 0, stream>>>(tokens, emb, wpack, wxt, biasv,
                                             proj0a, proj0b, proj1a, proj1b,
                                             h0a, h0b, hstate, Wfc, bfc, out, i);
    }
}